// Round 2
// baseline (1517.198 us; speedup 1.0000x reference)
//
#include <hip/hip_runtime.h>
#include <hip/hip_bf16.h>

#define T_STEPS 256
#define BATCH   512
#define HID     128
#define TBROWS  (T_STEPS * BATCH)
#define XSTRIDE 32
#define ROWS    16

__device__ __forceinline__ float sigf(float x) { return 1.0f / (1.0f + __expf(-x)); }
__device__ __forceinline__ float tanh_fast(float x) { return 2.0f / (1.0f + __expf(-2.0f * x)) - 1.0f; }

// ---------------------------------------------------------------------------
// Encoder: per block, ROWS rows. MLP 25->256->256->128->16 + loc/msg encoders.
// All fp32. Activations in LDS; weights streamed from global (L2-resident).
// Writes xcat[row][0..23] = [feat16 | loc4 | msg4] fp32 into workspace.
// ---------------------------------------------------------------------------
__global__ __launch_bounds__(256) void encoder_kernel(
    const float* __restrict__ img,
    const float* __restrict__ loc,
    const float* __restrict__ msg,
    const int*   __restrict__ done,
    const float* __restrict__ W1, const float* __restrict__ B1,
    const float* __restrict__ W2, const float* __restrict__ B2,
    const float* __restrict__ W3, const float* __restrict__ B3,
    const float* __restrict__ W4, const float* __restrict__ B4,
    const float* __restrict__ Wl, const float* __restrict__ Bl,
    const float* __restrict__ Wm, const float* __restrict__ Bm,
    float* __restrict__ xcat)
{
    __shared__ float xin[ROWS][28];    // 25 used
    __shared__ __align__(16) float a1[ROWS][260];   // stride 260 -> rows 16B aligned
    __shared__ __align__(16) float a2[ROWS][260];
    const int tid  = threadIdx.x;
    const int row0 = blockIdx.x * ROWS;

    // stage image rows, /255
    for (int idx = tid; idx < ROWS * 25; idx += 256) {
        const int r = idx / 25, k = idx - r * 25;
        xin[r][k] = img[(row0 + r) * 25 + k] * (1.0f / 255.0f);
    }
    __syncthreads();

    // L1: 25 -> 256. thread = neuron, loops rows.
    {
        const int n = tid;
        float w[25];
        #pragma unroll
        for (int k = 0; k < 25; ++k) w[k] = W1[n * 25 + k];
        const float bb = B1[n];
        #pragma unroll
        for (int r = 0; r < ROWS; ++r) {
            float acc = bb;
            #pragma unroll
            for (int k = 0; k < 25; ++k) acc = fmaf(w[k], xin[r][k], acc);
            a1[r][n] = fmaxf(acc, 0.0f);
        }
    }
    __syncthreads();

    // L2: 256 -> 256. thread = neuron, acc per row, float4 weight stream.
    {
        const int n = tid;
        float acc[ROWS];
        #pragma unroll
        for (int r = 0; r < ROWS; ++r) acc[r] = 0.0f;
        const float4* wp = reinterpret_cast<const float4*>(W2 + n * 256);
        #pragma unroll 4
        for (int j = 0; j < 64; j += 2) {
            const float4 wa = wp[j];
            const float4 wb = wp[j + 1];
            const int k0 = j * 4;
            #pragma unroll
            for (int r = 0; r < ROWS; ++r) {
                const float* ar = &a1[r][k0];
                float s = fmaf(wa.x, ar[0], fmaf(wa.y, ar[1], fmaf(wa.z, ar[2], wa.w * ar[3])));
                s = fmaf(wb.x, ar[4], fmaf(wb.y, ar[5], fmaf(wb.z, ar[6], fmaf(wb.w, ar[7], s))));
                acc[r] += s;
            }
        }
        const float bb = B2[n];
        #pragma unroll
        for (int r = 0; r < ROWS; ++r) a2[r][n] = fmaxf(acc[r] + bb, 0.0f);
    }
    __syncthreads();

    // L3: 256 -> 128. n = tid&127, each half of threads handles half the rows.
    // Output written into a1[.][0..127] (dead after L2).
    {
        const int n  = tid & 127;
        const int r0 = (tid >> 7) * (ROWS / 2);
        float acc[ROWS / 2];
        #pragma unroll
        for (int r = 0; r < ROWS / 2; ++r) acc[r] = 0.0f;
        const float4* wp = reinterpret_cast<const float4*>(W3 + n * 256);
        #pragma unroll 4
        for (int j = 0; j < 64; j += 2) {
            const float4 wa = wp[j];
            const float4 wb = wp[j + 1];
            const int k0 = j * 4;
            #pragma unroll
            for (int r = 0; r < ROWS / 2; ++r) {
                const float* ar = &a2[r0 + r][k0];
                float s = fmaf(wa.x, ar[0], fmaf(wa.y, ar[1], fmaf(wa.z, ar[2], wa.w * ar[3])));
                s = fmaf(wb.x, ar[4], fmaf(wb.y, ar[5], fmaf(wb.z, ar[6], fmaf(wb.w, ar[7], s))));
                acc[r] += s;
            }
        }
        const float bb = B3[n];
        #pragma unroll
        for (int r = 0; r < ROWS / 2; ++r) a1[r0 + r][n] = fmaxf(acc[r] + bb, 0.0f);
    }
    __syncthreads();

    // L4: 128 -> 16. thread -> (row = tid>>4, neuron = tid&15). Plus loc/msg.
    {
        const int r = tid >> 4;
        const int n = tid & 15;
        const float4* wp = reinterpret_cast<const float4*>(W4 + n * 128);
        float acc = 0.0f;
        #pragma unroll
        for (int j = 0; j < 32; j += 2) {
            const float4 wa = wp[j];
            const float4 wb = wp[j + 1];
            const float* ar = &a1[r][j * 4];
            float s = fmaf(wa.x, ar[0], fmaf(wa.y, ar[1], fmaf(wa.z, ar[2], wa.w * ar[3])));
            s = fmaf(wb.x, ar[4], fmaf(wb.y, ar[5], fmaf(wb.z, ar[6], fmaf(wb.w, ar[7], s))));
            acc += s;
        }
        acc += B4[n];
        xcat[(row0 + r) * XSTRIDE + n] = fmaxf(acc, 0.0f);

        if (tid < ROWS) {
            const int row = row0 + tid;
            const float l0 = loc[row * 2 + 0] * 0.1f;
            const float l1 = loc[row * 2 + 1] * 0.1f;
            #pragma unroll
            for (int c = 0; c < 4; ++c) {
                xcat[row * XSTRIDE + 16 + c] =
                    fmaf(Wl[c * 2 + 0], l0, fmaf(Wl[c * 2 + 1], l1, Bl[c]));
            }
            const float mm = (1.0f - (float)done[row]) * msg[row];
            #pragma unroll
            for (int c = 0; c < 4; ++c) {
                xcat[row * XSTRIDE + 20 + c] = fmaxf(fmaf(Wm[c], mm, Bm[c]), 0.0f);
            }
        }
    }
}

// ---------------------------------------------------------------------------
// LSTM scan: one block per batch element (batch elements are independent).
// 512 threads = 512 gate rows. Whh row in 128 fp32 VGPRs.
// h in LDS (fp32 broadcast reads via ds_read_b128); c in regs of t<128.
// ---------------------------------------------------------------------------
__global__ __launch_bounds__(512) void lstm_kernel(
    const float* __restrict__ xcat,
    const int*   __restrict__ done,
    const float* __restrict__ h0,
    const float* __restrict__ c0,
    const float* __restrict__ Wih, const float* __restrict__ bih,
    const float* __restrict__ Whh, const float* __restrict__ bhh,
    float* __restrict__ out)
{
    const int b = blockIdx.x;
    const int t = threadIdx.x;             // gate row 0..511 ([i|f|g|o] x 128)
    __shared__ __align__(16) float hsh[HID];
    __shared__ float gsh[4 * HID];

    // Whh row t: 128 fp32 in registers
    float whh[128];
    {
        const float4* wp = reinterpret_cast<const float4*>(Whh + t * HID);
        #pragma unroll
        for (int i = 0; i < 32; ++i) {
            const float4 v = wp[i];
            whh[i * 4 + 0] = v.x; whh[i * 4 + 1] = v.y;
            whh[i * 4 + 2] = v.z; whh[i * 4 + 3] = v.w;
        }
    }
    // Wih row t: 24 fp32
    float wih[24];
    {
        const float4* xp = reinterpret_cast<const float4*>(Wih + t * 24);
        #pragma unroll
        for (int i = 0; i < 6; ++i) {
            const float4 v = xp[i];
            wih[i * 4 + 0] = v.x; wih[i * 4 + 1] = v.y;
            wih[i * 4 + 2] = v.z; wih[i * 4 + 3] = v.w;
        }
    }
    const float bsum = bih[t] + bhh[t];

    float creg = 0.0f;
    if (t < HID) {
        hsh[t] = h0[b * HID + t];
        creg   = c0[b * HID + t];
    }
    __syncthreads();

    for (int s = 0; s < T_STEPS; ++s) {
        const int row = s * BATCH + b;
        const float mask = 1.0f - (float)done[row];

        // input contribution (xcat row broadcast via L1/L2)
        const float4* xr = reinterpret_cast<const float4*>(xcat + row * XSTRIDE);
        float xp_ = bsum;
        #pragma unroll
        for (int i = 0; i < 6; ++i) {
            const float4 v = xr[i];
            xp_ = fmaf(wih[i * 4 + 0], v.x, xp_);
            xp_ = fmaf(wih[i * 4 + 1], v.y, xp_);
            xp_ = fmaf(wih[i * 4 + 2], v.z, xp_);
            xp_ = fmaf(wih[i * 4 + 3], v.w, xp_);
        }

        // recurrent contribution, 4-way ILP (h masked => scale dot by mask)
        float a0 = 0.0f, a1 = 0.0f, a2 = 0.0f, a3 = 0.0f;
        const float4* hp = reinterpret_cast<const float4*>(hsh);
        #pragma unroll
        for (int j = 0; j < 32; ++j) {
            const float4 hv = hp[j];
            a0 = fmaf(whh[j * 4 + 0], hv.x, a0);
            a1 = fmaf(whh[j * 4 + 1], hv.y, a1);
            a2 = fmaf(whh[j * 4 + 2], hv.z, a2);
            a3 = fmaf(whh[j * 4 + 3], hv.w, a3);
        }
        const float acc = (a0 + a1) + (a2 + a3);
        gsh[t] = fmaf(mask, acc, xp_);
        __syncthreads();

        if (t < HID) {
            const float ig = gsh[t];
            const float fg = gsh[HID + t];
            const float gg = gsh[2 * HID + t];
            const float og = gsh[3 * HID + t];
            const float cn = sigf(fg) * (creg * mask) + sigf(ig) * tanh_fast(gg);
            const float hn = sigf(og) * tanh_fast(cn);
            creg = cn;
            hsh[t] = hn;
            out[row * HID + t] = hn;
        }
        __syncthreads();
    }

    if (t < HID) {
        out[TBROWS * HID + b * HID + t]               = hsh[t];
        out[TBROWS * HID + BATCH * HID + b * HID + t] = creg;
    }
}

extern "C" void kernel_launch(void* const* d_in, const int* in_sizes, int n_in,
                              void* d_out, int out_size, void* d_ws, size_t ws_size,
                              hipStream_t stream) {
    const float* img  = (const float*)d_in[0];
    const float* loc  = (const float*)d_in[1];
    const float* msg  = (const float*)d_in[2];
    const int*   done = (const int*)d_in[3];
    const float* h0   = (const float*)d_in[4];
    const float* c0   = (const float*)d_in[5];
    const float* W1   = (const float*)d_in[6];
    const float* B1   = (const float*)d_in[7];
    const float* W2   = (const float*)d_in[8];
    const float* B2   = (const float*)d_in[9];
    const float* W3   = (const float*)d_in[10];
    const float* B3   = (const float*)d_in[11];
    const float* W4   = (const float*)d_in[12];
    const float* B4   = (const float*)d_in[13];
    const float* Wl   = (const float*)d_in[14];
    const float* Bl   = (const float*)d_in[15];
    const float* Wm   = (const float*)d_in[16];
    const float* Bm   = (const float*)d_in[17];
    const float* Wih  = (const float*)d_in[18];
    const float* bih  = (const float*)d_in[19];
    const float* Whh  = (const float*)d_in[20];
    const float* bhh  = (const float*)d_in[21];

    float* xcat = (float*)d_ws;                       // [TBROWS][32] fp32, 16.8 MB
    float* out  = (float*)d_out;

    encoder_kernel<<<TBROWS / ROWS, 256, 0, stream>>>(
        img, loc, msg, done, W1, B1, W2, B2, W3, B3, W4, B4, Wl, Bl, Wm, Bm, xcat);
    lstm_kernel<<<BATCH, 512, 0, stream>>>(
        xcat, done, h0, c0, Wih, bih, Whh, bhh, out);
}

// Round 3
// 601.025 us; speedup vs baseline: 2.5243x; 2.5243x over previous
//
#include <hip/hip_runtime.h>
#include <hip/hip_bf16.h>

#define T_STEPS 256
#define BATCH   512
#define HID     128
#define TBROWS  (T_STEPS * BATCH)
#define XH_STRIDE 32          // xcat as f16, 32 ushorts per row (24 used)

typedef short  bh8   __attribute__((ext_vector_type(8)));   // 8 bf16 (MFMA A/B frag)
typedef float  f32x4 __attribute__((ext_vector_type(4)));   // MFMA C/D frag
typedef _Float16 h2  __attribute__((ext_vector_type(2)));   // half2 for fdot2

__device__ __forceinline__ float sigf(float x) { return 1.0f / (1.0f + __expf(-x)); }
__device__ __forceinline__ float tanh_fast(float x) { return 2.0f / (1.0f + __expf(-2.0f * x)) - 1.0f; }

__device__ __forceinline__ unsigned short f2bf_bits(float x) {
    union { float f; unsigned int u; } a; a.f = x;
    unsigned int r = a.u + 0x7fffu + ((a.u >> 16) & 1u);   // RNE
    return (unsigned short)(r >> 16);
}
__device__ __forceinline__ unsigned short f2h_bits(float x) {
    union { _Float16 h; unsigned short u; } z; z.h = (_Float16)x; return z.u;
}
__device__ __forceinline__ h2 u2h2(unsigned int u) {
    union { unsigned int u; h2 h; } z; z.u = u; return z.h;
}
__device__ __forceinline__ unsigned int pack2h(float a, float b) {
    union { _Float16 h[2]; unsigned int u; } z;
    z.h[0] = (_Float16)a; z.h[1] = (_Float16)b; return z.u;
}

#if __has_builtin(__builtin_amdgcn_fdot2)
#define FDOT2(a, b, c) __builtin_amdgcn_fdot2((a), (b), (c), false)
#else
__device__ __forceinline__ float FDOT2(h2 a, h2 b, float c) {
    return c + (float)a[0] * (float)b[0] + (float)a[1] * (float)b[1];
}
#endif

// ===========================================================================
// Prep: convert fp32 weights into (a) bf16 MFMA B-fragment blobs for the MLP,
// (b) half2-packed, thread-major LSTM weights, (c) fused bias.
// B-frag layout per layer: [kstep][ntile][lane][j] ushort,
//   value = W[ntile*16 + (lane&15)][kstep*32 + (lane>>4)*8 + j]  (0 if k>=K).
// ===========================================================================
__device__ __forceinline__ void fragstore(unsigned short* dst, const float* W,
                                          int i, int NT, int Kreal) {
    const int j    = i & 7;
    const int lane = (i >> 3) & 63;
    const int ts   = i >> 9;
    const int nt   = ts % NT;
    const int ks   = ts / NT;
    const int n = nt * 16 + (lane & 15);
    const int k = ks * 32 + (lane >> 4) * 8 + j;
    dst[i] = (k < Kreal) ? f2bf_bits(W[n * Kreal + k]) : (unsigned short)0;
}

#define NE1 8192     // 16 ntiles * 512
#define NE2 65536    // 8 ksteps * 16 ntiles * 512
#define NE3 32768    // 8 * 8 * 512
#define NE4 2048     // 4 * 1 * 512
#define NWHH 32768   // 4 gates * 64 kpairs * 128 units (uint)
#define NWIH 6144    // 4 * 12 * 128
#define NBS 512
#define PREP_TOTAL (NE1 + NE2 + NE3 + NE4 + NWHH + NWIH + NBS)   // 147968

__global__ __launch_bounds__(256) void prep_kernel(
    const float* __restrict__ W1, const float* __restrict__ W2,
    const float* __restrict__ W3, const float* __restrict__ W4,
    const float* __restrict__ Wih, const float* __restrict__ bih,
    const float* __restrict__ Whh, const float* __restrict__ bhh,
    unsigned short* __restrict__ w1f, unsigned short* __restrict__ w2f,
    unsigned short* __restrict__ w3f, unsigned short* __restrict__ w4f,
    unsigned int* __restrict__ whhf, unsigned int* __restrict__ wihf,
    float* __restrict__ bsum)
{
    int i = blockIdx.x * 256 + threadIdx.x;
    if (i < NE1) { fragstore(w1f, W1, i, 16, 25); return; }
    i -= NE1;
    if (i < NE2) { fragstore(w2f, W2, i, 16, 256); return; }
    i -= NE2;
    if (i < NE3) { fragstore(w3f, W3, i, 8, 256); return; }
    i -= NE3;
    if (i < NE4) { fragstore(w4f, W4, i, 1, 128); return; }
    i -= NE4;
    if (i < NWHH) {
        const int t = i & 127, gk = i >> 7, g = gk >> 6, kp = gk & 63;
        const int r = g * 128 + t;
        whhf[i] = pack2h(Whh[r * 128 + 2 * kp], Whh[r * 128 + 2 * kp + 1]);
        return;
    }
    i -= NWHH;
    if (i < NWIH) {
        const int t = i & 127, gk = i >> 7, g = gk / 12, kp = gk % 12;
        const int r = g * 128 + t;
        wihf[i] = pack2h(Wih[r * 24 + 2 * kp], Wih[r * 24 + 2 * kp + 1]);
        return;
    }
    i -= NWIH;
    if (i < NBS) bsum[i] = bih[i] + bhh[i];
}

// ===========================================================================
// Encoder: bf16 MFMA MLP 25->256->256->128->16, per-wave 16 rows, no barriers.
// Block = 256 thr (4 waves) = 64 rows. Acts in per-wave LDS (stride 264 pads
// banks). Weights read as pre-transposed coalesced B-frag blobs from ws.
// A-frag: A[m=lane&15][k=quad*8+j]; C/D: row=quad*4+reg, col=lane&15.
// Writes xcat_h[row][0..23] = f16([feat16 | loc4 | msg4]).
// ===========================================================================
#define ASTRIDE 264

__global__ __launch_bounds__(256) void encoder_kernel(
    const float* __restrict__ img,
    const float* __restrict__ loc,
    const float* __restrict__ msg,
    const int*   __restrict__ done,
    const float* __restrict__ B1, const float* __restrict__ B2,
    const float* __restrict__ B3, const float* __restrict__ B4,
    const float* __restrict__ Wl, const float* __restrict__ Bl,
    const float* __restrict__ Wm, const float* __restrict__ Bm,
    const unsigned short* __restrict__ w1f, const unsigned short* __restrict__ w2f,
    const unsigned short* __restrict__ w3f, const unsigned short* __restrict__ w4f,
    unsigned short* __restrict__ xcat_h)
{
    __shared__ unsigned short actA[4][16][ASTRIDE];
    __shared__ unsigned short actB[4][16][ASTRIDE];

    const int tid  = threadIdx.x;
    const int w    = tid >> 6;
    const int lane = tid & 63;
    const int m    = lane & 15;
    const int quad = lane >> 4;
    const int wrow0 = blockIdx.x * 64 + w * 16;    // first abs row of this wave

    // ---- loc/msg encoders (independent of MLP) ----
    if (tid < 64) {
        const int grow = blockIdx.x * 64 + tid;
        const float l0 = loc[grow * 2 + 0] * 0.1f;
        const float l1 = loc[grow * 2 + 1] * 0.1f;
        #pragma unroll
        for (int c = 0; c < 4; ++c)
            xcat_h[grow * XH_STRIDE + 16 + c] =
                f2h_bits(fmaf(Wl[c * 2 + 0], l0, fmaf(Wl[c * 2 + 1], l1, Bl[c])));
        const float mm = (1.0f - (float)done[grow]) * msg[grow];
        #pragma unroll
        for (int c = 0; c < 4; ++c)
            xcat_h[grow * XH_STRIDE + 20 + c] =
                f2h_bits(fmaxf(fmaf(Wm[c], mm, Bm[c]), 0.0f));
    }

    const f32x4 zero4 = {0.0f, 0.0f, 0.0f, 0.0f};

    // ---- L1: 25(pad32) -> 256, A built straight from global img ----
    {
        bh8 af;
        const int grow = wrow0 + m;
        #pragma unroll
        for (int j = 0; j < 8; ++j) {
            const int k = quad * 8 + j;
            const float v = (k < 25) ? img[grow * 25 + k] * (1.0f / 255.0f) : 0.0f;
            af[j] = (short)f2bf_bits(v);
        }
        f32x4 acc[16];
        #pragma unroll
        for (int nt = 0; nt < 16; ++nt) {
            const bh8 bf_ = *reinterpret_cast<const bh8*>(w1f + (nt * 64 + lane) * 8);
            acc[nt] = __builtin_amdgcn_mfma_f32_16x16x32_bf16(af, bf_, zero4, 0, 0, 0);
        }
        #pragma unroll
        for (int nt = 0; nt < 16; ++nt) {
            const float bb = B1[nt * 16 + m];
            #pragma unroll
            for (int r = 0; r < 4; ++r)
                actA[w][quad * 4 + r][nt * 16 + m] = f2bf_bits(fmaxf(acc[nt][r] + bb, 0.0f));
        }
    }

    // ---- L2: 256 -> 256 ----
    {
        f32x4 acc[16];
        #pragma unroll
        for (int nt = 0; nt < 16; ++nt) acc[nt] = zero4;
        #pragma unroll
        for (int ks = 0; ks < 8; ++ks) {
            const bh8 af = *reinterpret_cast<const bh8*>(&actA[w][m][ks * 32 + quad * 8]);
            const unsigned short* wp = w2f + ((ks * 16) * 64 + lane) * 8;
            #pragma unroll
            for (int nt = 0; nt < 16; ++nt) {
                const bh8 bf_ = *reinterpret_cast<const bh8*>(wp + nt * 512);
                acc[nt] = __builtin_amdgcn_mfma_f32_16x16x32_bf16(af, bf_, acc[nt], 0, 0, 0);
            }
        }
        #pragma unroll
        for (int nt = 0; nt < 16; ++nt) {
            const float bb = B2[nt * 16 + m];
            #pragma unroll
            for (int r = 0; r < 4; ++r)
                actB[w][quad * 4 + r][nt * 16 + m] = f2bf_bits(fmaxf(acc[nt][r] + bb, 0.0f));
        }
    }

    // ---- L3: 256 -> 128 ----
    {
        f32x4 acc[8];
        #pragma unroll
        for (int nt = 0; nt < 8; ++nt) acc[nt] = zero4;
        #pragma unroll
        for (int ks = 0; ks < 8; ++ks) {
            const bh8 af = *reinterpret_cast<const bh8*>(&actB[w][m][ks * 32 + quad * 8]);
            const unsigned short* wp = w3f + ((ks * 8) * 64 + lane) * 8;
            #pragma unroll
            for (int nt = 0; nt < 8; ++nt) {
                const bh8 bf_ = *reinterpret_cast<const bh8*>(wp + nt * 512);
                acc[nt] = __builtin_amdgcn_mfma_f32_16x16x32_bf16(af, bf_, acc[nt], 0, 0, 0);
            }
        }
        #pragma unroll
        for (int nt = 0; nt < 8; ++nt) {
            const float bb = B3[nt * 16 + m];
            #pragma unroll
            for (int r = 0; r < 4; ++r)
                actA[w][quad * 4 + r][nt * 16 + m] = f2bf_bits(fmaxf(acc[nt][r] + bb, 0.0f));
        }
    }

    // ---- L4: 128 -> 16, write f16 to xcat ----
    {
        f32x4 acc = zero4;
        #pragma unroll
        for (int ks = 0; ks < 4; ++ks) {
            const bh8 af = *reinterpret_cast<const bh8*>(&actA[w][m][ks * 32 + quad * 8]);
            const bh8 bf_ = *reinterpret_cast<const bh8*>(w4f + (ks * 64 + lane) * 8);
            acc = __builtin_amdgcn_mfma_f32_16x16x32_bf16(af, bf_, acc, 0, 0, 0);
        }
        const float bb = B4[m];
        #pragma unroll
        for (int r = 0; r < 4; ++r) {
            const int grow = wrow0 + quad * 4 + r;
            xcat_h[grow * XH_STRIDE + m] = f2h_bits(fmaxf(acc[r] + bb, 0.0f));
        }
    }
}

// ===========================================================================
// LSTM scan: block = 1 batch elem, 128 threads; thread t owns hidden unit t
// and all 4 gate rows (Whh rows as half2 in 256 VGPRs, fdot2 accumulation in
// fp32). h as f16 in double-buffered LDS -> 1 barrier/step. c, last-h in regs.
// ===========================================================================
__global__ __launch_bounds__(128) void lstm_kernel(
    const unsigned short* __restrict__ xcat_h,
    const int*   __restrict__ done,
    const float* __restrict__ h0,
    const float* __restrict__ c0,
    const unsigned int* __restrict__ whhf,   // [4][64][128] uint (half2)
    const unsigned int* __restrict__ wihf,   // [4][12][128] uint (half2)
    const float* __restrict__ bsum,          // [512] = bih + bhh
    float* __restrict__ out)
{
    const int b = blockIdx.x;
    const int t = threadIdx.x;
    __shared__ __align__(16) unsigned short hbuf[2][HID];

    h2 wh[4][64];
    #pragma unroll
    for (int g = 0; g < 4; ++g)
        #pragma unroll
        for (int kp = 0; kp < 64; ++kp)
            wh[g][kp] = u2h2(whhf[(g * 64 + kp) * 128 + t]);

    h2 wx[4][12];
    #pragma unroll
    for (int g = 0; g < 4; ++g)
        #pragma unroll
        for (int kp = 0; kp < 12; ++kp)
            wx[g][kp] = u2h2(wihf[(g * 12 + kp) * 128 + t]);

    float bs[4];
    #pragma unroll
    for (int g = 0; g < 4; ++g) bs[g] = bsum[g * 128 + t];

    float creg = c0[b * HID + t];
    float hn   = h0[b * HID + t];
    hbuf[0][t] = f2h_bits(hn);
    __syncthreads();

    int cur = 0;
    #pragma unroll 1
    for (int s = 0; s < T_STEPS; ++s) {
        const int row = s * BATCH + b;
        const float mask = 1.0f - (float)done[row];

        // input-side gates (xcat row is uniform across the block -> broadcast)
        const uint4* xr = reinterpret_cast<const uint4*>(xcat_h + (size_t)row * XH_STRIDE);
        const uint4 x0 = xr[0], x1 = xr[1], x2 = xr[2];
        const unsigned int xw[12] = {x0.x, x0.y, x0.z, x0.w,
                                     x1.x, x1.y, x1.z, x1.w,
                                     x2.x, x2.y, x2.z, x2.w};
        float g4[4];
        #pragma unroll
        for (int g = 0; g < 4; ++g) g4[g] = bs[g];
        #pragma unroll
        for (int kp = 0; kp < 12; ++kp) {
            const h2 xv = u2h2(xw[kp]);
            #pragma unroll
            for (int g = 0; g < 4; ++g) g4[g] = FDOT2(wx[g][kp], xv, g4[g]);
        }

        // recurrent gates
        float r4[4] = {0.0f, 0.0f, 0.0f, 0.0f};
        const uint4* hp = reinterpret_cast<const uint4*>(hbuf[cur]);
        #pragma unroll
        for (int q = 0; q < 16; ++q) {
            const uint4 hv = hp[q];
            const unsigned int he[4] = {hv.x, hv.y, hv.z, hv.w};
            #pragma unroll
            for (int e = 0; e < 4; ++e) {
                const h2 hh = u2h2(he[e]);
                const int kp = q * 4 + e;
                #pragma unroll
                for (int g = 0; g < 4; ++g) r4[g] = FDOT2(wh[g][kp], hh, r4[g]);
            }
        }

        const float gi = fmaf(mask, r4[0], g4[0]);
        const float gf = fmaf(mask, r4[1], g4[1]);
        const float gg = fmaf(mask, r4[2], g4[2]);
        const float go = fmaf(mask, r4[3], g4[3]);
        const float cn = sigf(gf) * (creg * mask) + sigf(gi) * tanh_fast(gg);
        hn   = sigf(go) * tanh_fast(cn);
        creg = cn;
        out[(size_t)row * HID + t] = hn;
        hbuf[cur ^ 1][t] = f2h_bits(hn);
        __syncthreads();
        cur ^= 1;
    }

    out[(size_t)TBROWS * HID + b * HID + t]               = hn;
    out[(size_t)TBROWS * HID + BATCH * HID + b * HID + t] = creg;
}

// ===========================================================================
extern "C" void kernel_launch(void* const* d_in, const int* in_sizes, int n_in,
                              void* d_out, int out_size, void* d_ws, size_t ws_size,
                              hipStream_t stream) {
    const float* img  = (const float*)d_in[0];
    const float* loc  = (const float*)d_in[1];
    const float* msg  = (const float*)d_in[2];
    const int*   done = (const int*)d_in[3];
    const float* h0   = (const float*)d_in[4];
    const float* c0   = (const float*)d_in[5];
    const float* W1   = (const float*)d_in[6];
    const float* B1   = (const float*)d_in[7];
    const float* W2   = (const float*)d_in[8];
    const float* B2   = (const float*)d_in[9];
    const float* W3   = (const float*)d_in[10];
    const float* B3   = (const float*)d_in[11];
    const float* W4   = (const float*)d_in[12];
    const float* B4   = (const float*)d_in[13];
    const float* Wl   = (const float*)d_in[14];
    const float* Bl   = (const float*)d_in[15];
    const float* Wm   = (const float*)d_in[16];
    const float* Bm   = (const float*)d_in[17];
    const float* Wih  = (const float*)d_in[18];
    const float* bih  = (const float*)d_in[19];
    const float* Whh  = (const float*)d_in[20];
    const float* bhh  = (const float*)d_in[21];

    // workspace layout
    char* wsb = (char*)d_ws;
    unsigned short* xcat_h = (unsigned short*)wsb;                   // 8 388 608 B
    unsigned short* w1f = (unsigned short*)(wsb + (size_t)TBROWS * XH_STRIDE * 2);
    unsigned short* w2f = w1f + NE1;
    unsigned short* w3f = w2f + NE2;
    unsigned short* w4f = w3f + NE3;
    unsigned int*   whhf = (unsigned int*)(w4f + NE4);
    unsigned int*   wihf = whhf + NWHH;
    float*          bsum = (float*)(wihf + NWIH);

    float* out = (float*)d_out;

    prep_kernel<<<(PREP_TOTAL + 255) / 256, 256, 0, stream>>>(
        W1, W2, W3, W4, Wih, bih, Whh, bhh,
        w1f, w2f, w3f, w4f, whhf, wihf, bsum);
    encoder_kernel<<<TBROWS / 64, 256, 0, stream>>>(
        img, loc, msg, done, B1, B2, B3, B4, Wl, Bl, Wm, Bm,
        w1f, w2f, w3f, w4f, xcat_h);
    lstm_kernel<<<BATCH, 128, 0, stream>>>(
        xcat_h, done, h0, c0, whhf, wihf, bsum, out);
}

// Round 4
// 413.262 us; speedup vs baseline: 3.6713x; 1.4543x over previous
//
#include <hip/hip_runtime.h>
#include <hip/hip_bf16.h>

#define T_STEPS 256
#define BATCH   512
#define HID     128
#define TBROWS  (T_STEPS * BATCH)
#define XH_STRIDE 32          // xcat as f16, 32 ushorts per row (24 used)

typedef short  bh8   __attribute__((ext_vector_type(8)));   // 8 bf16 (MFMA A/B frag)
typedef _Float16 h8  __attribute__((ext_vector_type(8)));   // 8 f16  (MFMA A/B frag)
typedef float  f32x4 __attribute__((ext_vector_type(4)));   // MFMA C/D frag

__device__ __forceinline__ unsigned short f2bf_bits(float x) {
    union { float f; unsigned int u; } a; a.f = x;
    unsigned int r = a.u + 0x7fffu + ((a.u >> 16) & 1u);   // RNE
    return (unsigned short)(r >> 16);
}
__device__ __forceinline__ unsigned short f2h_bits(float x) {
    union { _Float16 h; unsigned short u; } z; z.h = (_Float16)x; return z.u;
}
__device__ __forceinline__ unsigned int pack2h(float a, float b) {
    union { _Float16 h[2]; unsigned int u; } z;
    z.h[0] = (_Float16)a; z.h[1] = (_Float16)b; return z.u;
}

#if __has_builtin(__builtin_amdgcn_rcpf)
__device__ __forceinline__ float frcp(float x) { return __builtin_amdgcn_rcpf(x); }
#else
__device__ __forceinline__ float frcp(float x) { return 1.0f / x; }
#endif
#if __has_builtin(__builtin_amdgcn_exp2f)
__device__ __forceinline__ float fexp2(float x) { return __builtin_amdgcn_exp2f(x); }
#else
__device__ __forceinline__ float fexp2(float x) { return __expf(x * 0.6931471806f); }
#endif
#define LOG2E 1.442695041f
__device__ __forceinline__ float sigf(float x) {
    return frcp(1.0f + fexp2(-x * LOG2E));
}
__device__ __forceinline__ float tanh_fast(float x) {
    return fmaf(-2.0f, frcp(1.0f + fexp2(x * (2.0f * LOG2E))), 1.0f);
}

// ===========================================================================
// Prep: (a) bf16 B-frag blobs for the MLP encoder (unchanged from round 3),
// (b) f16 A-frag blob for the LSTM combined weight W_comb[512 x 160]
//     (k<128 -> Whh, 128<=k<152 -> Wih, else 0), (c) fused gate bias.
// A-frag layout: [mtile(32)][ktile(5)][lane(64)][j(8)],
//   value = Wc[mt*16 + (lane&15)][kt*32 + (lane>>4)*8 + j], f16.
// ===========================================================================
__device__ __forceinline__ void fragstore(unsigned short* dst, const float* W,
                                          int i, int NT, int Kreal) {
    const int j    = i & 7;
    const int lane = (i >> 3) & 63;
    const int ts   = i >> 9;
    const int nt   = ts % NT;
    const int ks   = ts / NT;
    const int n = nt * 16 + (lane & 15);
    const int k = ks * 32 + (lane >> 4) * 8 + j;
    dst[i] = (k < Kreal) ? f2bf_bits(W[n * Kreal + k]) : (unsigned short)0;
}

#define NE1 8192     // 16 ntiles * 512
#define NE2 65536    // 8 ksteps * 16 ntiles * 512
#define NE3 32768    // 8 * 8 * 512
#define NE4 2048     // 4 * 1 * 512
#define NWC 81920    // 32 mtiles * 5 ktiles * 64 * 8  (LSTM A-frags, f16)
#define NBS 512
#define PREP_TOTAL (NE1 + NE2 + NE3 + NE4 + NWC + NBS)   // 190976

__global__ __launch_bounds__(256) void prep_kernel(
    const float* __restrict__ W1, const float* __restrict__ W2,
    const float* __restrict__ W3, const float* __restrict__ W4,
    const float* __restrict__ Wih, const float* __restrict__ bih,
    const float* __restrict__ Whh, const float* __restrict__ bhh,
    unsigned short* __restrict__ w1f, unsigned short* __restrict__ w2f,
    unsigned short* __restrict__ w3f, unsigned short* __restrict__ w4f,
    unsigned short* __restrict__ wcf, float* __restrict__ bsum)
{
    int i = blockIdx.x * 256 + threadIdx.x;
    if (i < NE1) { fragstore(w1f, W1, i, 16, 25); return; }
    i -= NE1;
    if (i < NE2) { fragstore(w2f, W2, i, 16, 256); return; }
    i -= NE2;
    if (i < NE3) { fragstore(w3f, W3, i, 8, 256); return; }
    i -= NE3;
    if (i < NE4) { fragstore(w4f, W4, i, 1, 128); return; }
    i -= NE4;
    if (i < NWC) {
        const int j    = i & 7;
        const int lane = (i >> 3) & 63;
        const int ts   = i >> 9;          // mt*5 + kt
        const int mt   = ts / 5;
        const int kt   = ts - mt * 5;
        const int m = mt * 16 + (lane & 15);
        const int k = kt * 32 + (lane >> 4) * 8 + j;
        float v = 0.0f;
        if (k < 128)      v = Whh[m * 128 + k];
        else if (k < 152) v = Wih[m * 24 + (k - 128)];
        wcf[i] = f2h_bits(v);
        return;
    }
    i -= NWC;
    if (i < NBS) bsum[i] = bih[i] + bhh[i];
}

// ===========================================================================
// Encoder (unchanged from round 3): bf16 MFMA MLP 25->256->256->128->16,
// per-wave 16 rows, no barriers. Writes xcat_h[row][0..23] f16.
// ===========================================================================
#define ASTRIDE 264

__global__ __launch_bounds__(256) void encoder_kernel(
    const float* __restrict__ img,
    const float* __restrict__ loc,
    const float* __restrict__ msg,
    const int*   __restrict__ done,
    const float* __restrict__ B1, const float* __restrict__ B2,
    const float* __restrict__ B3, const float* __restrict__ B4,
    const float* __restrict__ Wl, const float* __restrict__ Bl,
    const float* __restrict__ Wm, const float* __restrict__ Bm,
    const unsigned short* __restrict__ w1f, const unsigned short* __restrict__ w2f,
    const unsigned short* __restrict__ w3f, const unsigned short* __restrict__ w4f,
    unsigned short* __restrict__ xcat_h)
{
    __shared__ unsigned short actA[4][16][ASTRIDE];
    __shared__ unsigned short actB[4][16][ASTRIDE];

    const int tid  = threadIdx.x;
    const int w    = tid >> 6;
    const int lane = tid & 63;
    const int m    = lane & 15;
    const int quad = lane >> 4;
    const int wrow0 = blockIdx.x * 64 + w * 16;

    if (tid < 64) {
        const int grow = blockIdx.x * 64 + tid;
        const float l0 = loc[grow * 2 + 0] * 0.1f;
        const float l1 = loc[grow * 2 + 1] * 0.1f;
        #pragma unroll
        for (int c = 0; c < 4; ++c)
            xcat_h[grow * XH_STRIDE + 16 + c] =
                f2h_bits(fmaf(Wl[c * 2 + 0], l0, fmaf(Wl[c * 2 + 1], l1, Bl[c])));
        const float mm = (1.0f - (float)done[grow]) * msg[grow];
        #pragma unroll
        for (int c = 0; c < 4; ++c)
            xcat_h[grow * XH_STRIDE + 20 + c] =
                f2h_bits(fmaxf(fmaf(Wm[c], mm, Bm[c]), 0.0f));
    }

    const f32x4 zero4 = {0.0f, 0.0f, 0.0f, 0.0f};

    // L1: 25(pad32) -> 256
    {
        bh8 af;
        const int grow = wrow0 + m;
        #pragma unroll
        for (int j = 0; j < 8; ++j) {
            const int k = quad * 8 + j;
            const float v = (k < 25) ? img[grow * 25 + k] * (1.0f / 255.0f) : 0.0f;
            af[j] = (short)f2bf_bits(v);
        }
        f32x4 acc[16];
        #pragma unroll
        for (int nt = 0; nt < 16; ++nt) {
            const bh8 bf_ = *reinterpret_cast<const bh8*>(w1f + (nt * 64 + lane) * 8);
            acc[nt] = __builtin_amdgcn_mfma_f32_16x16x32_bf16(af, bf_, zero4, 0, 0, 0);
        }
        #pragma unroll
        for (int nt = 0; nt < 16; ++nt) {
            const float bb = B1[nt * 16 + m];
            #pragma unroll
            for (int r = 0; r < 4; ++r)
                actA[w][quad * 4 + r][nt * 16 + m] = f2bf_bits(fmaxf(acc[nt][r] + bb, 0.0f));
        }
    }

    // L2: 256 -> 256
    {
        f32x4 acc[16];
        #pragma unroll
        for (int nt = 0; nt < 16; ++nt) acc[nt] = zero4;
        #pragma unroll
        for (int ks = 0; ks < 8; ++ks) {
            const bh8 af = *reinterpret_cast<const bh8*>(&actA[w][m][ks * 32 + quad * 8]);
            const unsigned short* wp = w2f + ((ks * 16) * 64 + lane) * 8;
            #pragma unroll
            for (int nt = 0; nt < 16; ++nt) {
                const bh8 bf_ = *reinterpret_cast<const bh8*>(wp + nt * 512);
                acc[nt] = __builtin_amdgcn_mfma_f32_16x16x32_bf16(af, bf_, acc[nt], 0, 0, 0);
            }
        }
        #pragma unroll
        for (int nt = 0; nt < 16; ++nt) {
            const float bb = B2[nt * 16 + m];
            #pragma unroll
            for (int r = 0; r < 4; ++r)
                actB[w][quad * 4 + r][nt * 16 + m] = f2bf_bits(fmaxf(acc[nt][r] + bb, 0.0f));
        }
    }

    // L3: 256 -> 128
    {
        f32x4 acc[8];
        #pragma unroll
        for (int nt = 0; nt < 8; ++nt) acc[nt] = zero4;
        #pragma unroll
        for (int ks = 0; ks < 8; ++ks) {
            const bh8 af = *reinterpret_cast<const bh8*>(&actB[w][m][ks * 32 + quad * 8]);
            const unsigned short* wp = w3f + ((ks * 8) * 64 + lane) * 8;
            #pragma unroll
            for (int nt = 0; nt < 8; ++nt) {
                const bh8 bf_ = *reinterpret_cast<const bh8*>(wp + nt * 512);
                acc[nt] = __builtin_amdgcn_mfma_f32_16x16x32_bf16(af, bf_, acc[nt], 0, 0, 0);
            }
        }
        #pragma unroll
        for (int nt = 0; nt < 8; ++nt) {
            const float bb = B3[nt * 16 + m];
            #pragma unroll
            for (int r = 0; r < 4; ++r)
                actA[w][quad * 4 + r][nt * 16 + m] = f2bf_bits(fmaxf(acc[nt][r] + bb, 0.0f));
        }
    }

    // L4: 128 -> 16, write f16 to xcat
    {
        f32x4 acc = zero4;
        #pragma unroll
        for (int ks = 0; ks < 4; ++ks) {
            const bh8 af = *reinterpret_cast<const bh8*>(&actA[w][m][ks * 32 + quad * 8]);
            const bh8 bf_ = *reinterpret_cast<const bh8*>(w4f + (ks * 64 + lane) * 8);
            acc = __builtin_amdgcn_mfma_f32_16x16x32_bf16(af, bf_, acc, 0, 0, 0);
        }
        const float bb = B4[m];
        #pragma unroll
        for (int r = 0; r < 4; ++r) {
            const int grow = wrow0 + quad * 4 + r;
            xcat_h[grow * XH_STRIDE + m] = f2h_bits(fmaxf(acc[r] + bb, 0.0f));
        }
    }
}

// ===========================================================================
// LSTM scan, MFMA version. Block = 16 batch elems, 512 threads (8 waves).
// Per step: gates[512x16] = Wc[512x160] @ [h;x][160x16] via f16 MFMA.
// Wave w owns gate tiles {w, w+8, w+16, w+24} -> lane holds i/f/g/o for the
// same 4 units in regs (no gate exchange). [h;x] double-buffered in LDS,
// 1 barrier/step. done prefetched 2 steps, xcat 1 step ahead. c in regs.
// ===========================================================================
#define HXS 168      // LDS row stride in shorts (336 B: 16B-aligned, 2-way banks)

__global__ __launch_bounds__(512, 2) void lstm_kernel(
    const unsigned short* __restrict__ xcat_h,
    const int*   __restrict__ done,
    const float* __restrict__ h0,
    const float* __restrict__ c0,
    const unsigned short* __restrict__ wcf,   // A-frag blob [32][5][64][8] f16
    const float* __restrict__ bsum,           // [512] = bih + bhh
    float* __restrict__ out)
{
    __shared__ unsigned short hx[2][16][HXS];

    const int tid  = threadIdx.x;
    const int w    = tid >> 6;        // wave 0..7 = unit-group
    const int lane = tid & 63;
    const int n    = lane & 15;       // batch column within block
    const int quad = lane >> 4;
    const int bb   = blockIdx.x * 16;
    const int u0   = w * 16 + quad * 4;   // first owned unit

    // weights: A-frags for tiles mt = g*8 + w, all 5 ktiles  (80 VGPRs)
    h8 wf[4][5];
    #pragma unroll
    for (int g = 0; g < 4; ++g)
        #pragma unroll
        for (int kt = 0; kt < 5; ++kt)
            wf[g][kt] = *reinterpret_cast<const h8*>(
                wcf + (size_t)(((g * 8 + w) * 5 + kt) * 64 + lane) * 8);

    // fused bias for owned rows
    float bi[4][4];
    #pragma unroll
    for (int g = 0; g < 4; ++g)
        #pragma unroll
        for (int r = 0; r < 4; ++r)
            bi[g][r] = bsum[g * 128 + u0 + r];

    // c state
    float c_[4];
    {
        const float4 cv = *reinterpret_cast<const float4*>(c0 + (size_t)(bb + n) * HID + u0);
        c_[0] = cv.x; c_[1] = cv.y; c_[2] = cv.z; c_[3] = cv.w;
    }

    // zero the k=152..159 pad of both buffers (never written elsewhere)
    if (tid < 128) {
        const int b_ = tid >> 6, r_ = (tid >> 2) & 15, j_ = tid & 3;
        *reinterpret_cast<unsigned int*>(&hx[b_][r_][152 + 2 * j_]) = 0u;
    }
    // h0 * mask(0) -> buf0
    for (int i = tid; i < 16 * HID; i += 512) {
        const int nn = i >> 7, uu = i & 127;
        const float m0 = 1.0f - (float)done[bb + nn];
        hx[0][nn][uu] = f2h_bits(h0[(size_t)(bb + nn) * HID + uu] * m0);
    }
    // x(0) -> buf0
    if (tid < 192) {
        const int nl = tid / 12, kp = tid - nl * 12;
        const unsigned int v = *reinterpret_cast<const unsigned int*>(
            xcat_h + (size_t)(bb + nl) * XH_STRIDE + 2 * kp);
        *reinterpret_cast<unsigned int*>(&hx[0][nl][128 + 2 * kp]) = v;
    }
    int mc_i = done[bb + n];              // done(0) for my column
    int mn_i = done[BATCH + bb + n];      // done(1)
    __syncthreads();

    float hn[4] = {0.0f, 0.0f, 0.0f, 0.0f};

    #pragma unroll 2
    for (int s = 0; s < T_STEPS; ++s) {
        const int buf = s & 1, nbuf = buf ^ 1;

        // B-frags for my batch column
        h8 bf[5];
        #pragma unroll
        for (int kt = 0; kt < 5; ++kt)
            bf[kt] = *reinterpret_cast<const h8*>(&hx[buf][n][kt * 32 + quad * 8]);

        // prefetch x(s+1) and done(s+2)
        unsigned int xreg = 0;
        if (tid < 192) {
            const int nl = tid / 12, kp = tid - nl * 12;
            const int rowx = (s + 1 < T_STEPS ? s + 1 : T_STEPS - 1) * BATCH + bb + nl;
            xreg = *reinterpret_cast<const unsigned int*>(
                xcat_h + (size_t)rowx * XH_STRIDE + 2 * kp);
        }
        const int mf_i = done[(s + 2 < T_STEPS ? s + 2 : T_STEPS - 1) * BATCH + bb + n];

        // MFMA: gates = Wc @ [h;x] + bias
        f32x4 acc[4];
        #pragma unroll
        for (int g = 0; g < 4; ++g) {
            acc[g][0] = bi[g][0]; acc[g][1] = bi[g][1];
            acc[g][2] = bi[g][2]; acc[g][3] = bi[g][3];
        }
        #pragma unroll
        for (int kt = 0; kt < 5; ++kt)
            #pragma unroll
            for (int g = 0; g < 4; ++g)
                acc[g] = __builtin_amdgcn_mfma_f32_16x16x32_f16(wf[g][kt], bf[kt], acc[g], 0, 0, 0);

        // elementwise gate math for my 4 units, batch column n
        const float mcur = 1.0f - (float)mc_i;
        const float mnxt = 1.0f - (float)mn_i;
        #pragma unroll
        for (int r = 0; r < 4; ++r) {
            const float gi = acc[0][r], gf = acc[1][r];
            const float gg = acc[2][r], go = acc[3][r];
            const float cn = sigf(gf) * (c_[r] * mcur) + sigf(gi) * tanh_fast(gg);
            hn[r] = sigf(go) * tanh_fast(cn);
            c_[r] = cn;
        }

        // store h(s) (unmasked) to out
        const int row = s * BATCH + bb + n;
        float4 ov; ov.x = hn[0]; ov.y = hn[1]; ov.z = hn[2]; ov.w = hn[3];
        *reinterpret_cast<float4*>(out + (size_t)row * HID + u0) = ov;

        // write h(s)*mask(s+1) and x(s+1) into the other buffer
        *reinterpret_cast<unsigned int*>(&hx[nbuf][n][u0])     = pack2h(hn[0] * mnxt, hn[1] * mnxt);
        *reinterpret_cast<unsigned int*>(&hx[nbuf][n][u0 + 2]) = pack2h(hn[2] * mnxt, hn[3] * mnxt);
        if (tid < 192) {
            const int nl = tid / 12, kp = tid - nl * 12;
            *reinterpret_cast<unsigned int*>(&hx[nbuf][nl][128 + 2 * kp]) = xreg;
        }
        mc_i = mn_i; mn_i = mf_i;
        __syncthreads();
    }

    // hT, cT
    const size_t base = (size_t)TBROWS * HID;
    float4 hv; hv.x = hn[0]; hv.y = hn[1]; hv.z = hn[2]; hv.w = hn[3];
    *reinterpret_cast<float4*>(out + base + (size_t)(bb + n) * HID + u0) = hv;
    float4 cvo; cvo.x = c_[0]; cvo.y = c_[1]; cvo.z = c_[2]; cvo.w = c_[3];
    *reinterpret_cast<float4*>(out + base + (size_t)BATCH * HID + (size_t)(bb + n) * HID + u0) = cvo;
}

// ===========================================================================
extern "C" void kernel_launch(void* const* d_in, const int* in_sizes, int n_in,
                              void* d_out, int out_size, void* d_ws, size_t ws_size,
                              hipStream_t stream) {
    const float* img  = (const float*)d_in[0];
    const float* loc  = (const float*)d_in[1];
    const float* msg  = (const float*)d_in[2];
    const int*   done = (const int*)d_in[3];
    const float* h0   = (const float*)d_in[4];
    const float* c0   = (const float*)d_in[5];
    const float* W1   = (const float*)d_in[6];
    const float* B1   = (const float*)d_in[7];
    const float* W2   = (const float*)d_in[8];
    const float* B2   = (const float*)d_in[9];
    const float* W3   = (const float*)d_in[10];
    const float* B3   = (const float*)d_in[11];
    const float* W4   = (const float*)d_in[12];
    const float* B4   = (const float*)d_in[13];
    const float* Wl   = (const float*)d_in[14];
    const float* Bl   = (const float*)d_in[15];
    const float* Wm   = (const float*)d_in[16];
    const float* Bm   = (const float*)d_in[17];
    const float* Wih  = (const float*)d_in[18];
    const float* bih  = (const float*)d_in[19];
    const float* Whh  = (const float*)d_in[20];
    const float* bhh  = (const float*)d_in[21];

    // workspace layout
    char* wsb = (char*)d_ws;
    unsigned short* xcat_h = (unsigned short*)wsb;                   // 8 388 608 B
    unsigned short* w1f = (unsigned short*)(wsb + (size_t)TBROWS * XH_STRIDE * 2);
    unsigned short* w2f = w1f + NE1;
    unsigned short* w3f = w2f + NE2;
    unsigned short* w4f = w3f + NE3;
    unsigned short* wcf = w4f + NE4;
    float*          bsum = (float*)(wcf + NWC);

    float* out = (float*)d_out;

    prep_kernel<<<(PREP_TOTAL + 255) / 256, 256, 0, stream>>>(
        W1, W2, W3, W4, Wih, bih, Whh, bhh,
        w1f, w2f, w3f, w4f, wcf, bsum);
    encoder_kernel<<<TBROWS / 64, 256, 0, stream>>>(
        img, loc, msg, done, B1, B2, B3, B4, Wl, Bl, Wm, Bm,
        w1f, w2f, w3f, w4f, xcat_h);
    lstm_kernel<<<BATCH / 16, 512, 0, stream>>>(
        xcat_h, done, h0, c0, wcf, bsum, out);
}

// Round 5
// 402.809 us; speedup vs baseline: 3.7665x; 1.0260x over previous
//
#include <hip/hip_runtime.h>
#include <hip/hip_bf16.h>

#define T_STEPS 256
#define BATCH   512
#define HID     128
#define TBROWS  (T_STEPS * BATCH)
#define XH_STRIDE 32          // xcat as f16, 32 ushorts per row (24 used)

typedef short  bh8   __attribute__((ext_vector_type(8)));   // 8 bf16 (MFMA A/B frag)
typedef _Float16 h8  __attribute__((ext_vector_type(8)));   // 8 f16  (MFMA A/B frag)
typedef float  f32x4 __attribute__((ext_vector_type(4)));   // MFMA C/D frag

__device__ __forceinline__ unsigned short f2bf_bits(float x) {
    union { float f; unsigned int u; } a; a.f = x;
    unsigned int r = a.u + 0x7fffu + ((a.u >> 16) & 1u);   // RNE
    return (unsigned short)(r >> 16);
}
__device__ __forceinline__ unsigned short f2h_bits(float x) {
    union { _Float16 h; unsigned short u; } z; z.h = (_Float16)x; return z.u;
}
__device__ __forceinline__ unsigned int pack2h(float a, float b) {
    union { _Float16 h[2]; unsigned int u; } z;
    z.h[0] = (_Float16)a; z.h[1] = (_Float16)b; return z.u;
}
__device__ __forceinline__ unsigned int pack2bf(float a, float b) {
    return (unsigned int)f2bf_bits(a) | ((unsigned int)f2bf_bits(b) << 16);
}

#if __has_builtin(__builtin_amdgcn_rcpf)
__device__ __forceinline__ float frcp(float x) { return __builtin_amdgcn_rcpf(x); }
#else
__device__ __forceinline__ float frcp(float x) { return 1.0f / x; }
#endif
#if __has_builtin(__builtin_amdgcn_exp2f)
__device__ __forceinline__ float fexp2(float x) { return __builtin_amdgcn_exp2f(x); }
#else
__device__ __forceinline__ float fexp2(float x) { return __expf(x * 0.6931471806f); }
#endif
#define LOG2E 1.442695041f
__device__ __forceinline__ float sigf(float x) {
    return frcp(1.0f + fexp2(-x * LOG2E));
}
__device__ __forceinline__ float tanh_fast(float x) {
    return fmaf(-2.0f, frcp(1.0f + fexp2(x * (2.0f * LOG2E))), 1.0f);
}

// ===========================================================================
// Prep (unchanged from round 4): bf16 frag blobs for MLP, f16 A-frag blob for
// the LSTM combined weight Wc[512x160] (k<128 Whh, 128<=k<152 Wih, else 0),
// fused gate bias. Frag layout (A and B share the pattern on 16x16x32):
//   blob[(tile*KT + kt)*512 + lane*8 + j] = W[tile*16 + (lane&15)][kt*32 + (lane>>4)*8 + j]
// ===========================================================================
__device__ __forceinline__ void fragstore(unsigned short* dst, const float* W,
                                          int i, int NT, int Kreal) {
    const int j    = i & 7;
    const int lane = (i >> 3) & 63;
    const int ts   = i >> 9;
    const int nt   = ts % NT;
    const int ks   = ts / NT;
    const int n = nt * 16 + (lane & 15);
    const int k = ks * 32 + (lane >> 4) * 8 + j;
    dst[i] = (k < Kreal) ? f2bf_bits(W[n * Kreal + k]) : (unsigned short)0;
}

#define NE1 8192     // 16 tiles * 512
#define NE2 65536    // 8 kt * 16 tiles * 512
#define NE3 32768    // 8 * 8 * 512
#define NE4 2048     // 4 * 1 * 512
#define NWC 81920    // 32 mtiles * 5 ktiles * 64 * 8  (LSTM A-frags, f16)
#define NBS 512
#define PREP_TOTAL (NE1 + NE2 + NE3 + NE4 + NWC + NBS)   // 190976

__global__ __launch_bounds__(256) void prep_kernel(
    const float* __restrict__ W1, const float* __restrict__ W2,
    const float* __restrict__ W3, const float* __restrict__ W4,
    const float* __restrict__ Wih, const float* __restrict__ bih,
    const float* __restrict__ Whh, const float* __restrict__ bhh,
    unsigned short* __restrict__ w1f, unsigned short* __restrict__ w2f,
    unsigned short* __restrict__ w3f, unsigned short* __restrict__ w4f,
    unsigned short* __restrict__ wcf, float* __restrict__ bsum)
{
    int i = blockIdx.x * 256 + threadIdx.x;
    if (i < NE1) { fragstore(w1f, W1, i, 16, 25); return; }
    i -= NE1;
    if (i < NE2) { fragstore(w2f, W2, i, 16, 256); return; }
    i -= NE2;
    if (i < NE3) { fragstore(w3f, W3, i, 8, 256); return; }
    i -= NE3;
    if (i < NE4) { fragstore(w4f, W4, i, 1, 128); return; }
    i -= NE4;
    if (i < NWC) {
        const int j    = i & 7;
        const int lane = (i >> 3) & 63;
        const int ts   = i >> 9;          // mt*5 + kt
        const int mt   = ts / 5;
        const int kt   = ts - mt * 5;
        const int m = mt * 16 + (lane & 15);
        const int k = kt * 32 + (lane >> 4) * 8 + j;
        float v = 0.0f;
        if (k < 128)      v = Whh[m * 128 + k];
        else if (k < 152) v = Wih[m * 24 + (k - 128)];
        wcf[i] = f2h_bits(v);
        return;
    }
    i -= NWC;
    if (i < NBS) bsum[i] = bih[i] + bhh[i];
}

// ===========================================================================
// Encoder v2: weights are the A operand, samples the B operand.
// Wave = 32 samples (2 sample-groups share every A-frag -> half the L2
// weight traffic). Acts in LDS as [sample][neuron] bf16: C output (row =
// out-neuron, col = sample) packs 4 consecutive neurons -> ds_write_b64;
// next layer's B-frag (k-contig per lane) -> ds_read_b128. No transposes.
// Block = 256 thr (4 waves) = 128 samples; grid = TBROWS/128 = 1024.
// ===========================================================================
#define ASTRIDE 264

__global__ __launch_bounds__(256) void encoder_kernel(
    const float* __restrict__ img,
    const float* __restrict__ loc,
    const float* __restrict__ msg,
    const int*   __restrict__ done,
    const float* __restrict__ B1, const float* __restrict__ B2,
    const float* __restrict__ B3, const float* __restrict__ B4,
    const float* __restrict__ Wl, const float* __restrict__ Bl,
    const float* __restrict__ Wm, const float* __restrict__ Bm,
    const unsigned short* __restrict__ w1f, const unsigned short* __restrict__ w2f,
    const unsigned short* __restrict__ w3f, const unsigned short* __restrict__ w4f,
    unsigned short* __restrict__ xcat_h)
{
    __shared__ __align__(16) unsigned short actA[4][32][ASTRIDE];
    __shared__ __align__(16) unsigned short actB[4][32][ASTRIDE];

    const int tid  = threadIdx.x;
    const int w    = tid >> 6;
    const int lane = tid & 63;
    const int n    = lane & 15;       // sample within group
    const int quad = lane >> 4;
    const int wrow0 = blockIdx.x * 128 + w * 32;

    // loc/msg encoders: 128 samples per block, 1 thread each
    if (tid < 128) {
        const int grow = blockIdx.x * 128 + tid;
        const float l0 = loc[(size_t)grow * 2 + 0] * 0.1f;
        const float l1 = loc[(size_t)grow * 2 + 1] * 0.1f;
        #pragma unroll
        for (int c = 0; c < 4; ++c)
            xcat_h[(size_t)grow * XH_STRIDE + 16 + c] =
                f2h_bits(fmaf(Wl[c * 2 + 0], l0, fmaf(Wl[c * 2 + 1], l1, Bl[c])));
        const float mm = (1.0f - (float)done[grow]) * msg[grow];
        #pragma unroll
        for (int c = 0; c < 4; ++c)
            xcat_h[(size_t)grow * XH_STRIDE + 20 + c] =
                f2h_bits(fmaxf(fmaf(Wm[c], mm, Bm[c]), 0.0f));
    }

    const f32x4 zero4 = {0.0f, 0.0f, 0.0f, 0.0f};

    // ---- L1: 25(pad32) -> 256 ----
    {
        bh8 bimg[2];
        #pragma unroll
        for (int sg = 0; sg < 2; ++sg) {
            const size_t grow = wrow0 + sg * 16 + n;
            #pragma unroll
            for (int j = 0; j < 8; ++j) {
                const int k = quad * 8 + j;
                const float v = (k < 25) ? img[grow * 25 + k] * (1.0f / 255.0f) : 0.0f;
                bimg[sg][j] = (short)f2bf_bits(v);
            }
        }
        f32x4 a1[16][2];
        #pragma unroll
        for (int mt = 0; mt < 16; ++mt) {
            const bh8 a = *reinterpret_cast<const bh8*>(w1f + (size_t)(mt * 64 + lane) * 8);
            a1[mt][0] = __builtin_amdgcn_mfma_f32_16x16x32_bf16(a, bimg[0], zero4, 0, 0, 0);
            a1[mt][1] = __builtin_amdgcn_mfma_f32_16x16x32_bf16(a, bimg[1], zero4, 0, 0, 0);
        }
        #pragma unroll
        for (int mt = 0; mt < 16; ++mt) {
            const float4 bv = *reinterpret_cast<const float4*>(B1 + mt * 16 + quad * 4);
            #pragma unroll
            for (int sg = 0; sg < 2; ++sg) {
                const float v0 = fmaxf(a1[mt][sg][0] + bv.x, 0.0f);
                const float v1 = fmaxf(a1[mt][sg][1] + bv.y, 0.0f);
                const float v2 = fmaxf(a1[mt][sg][2] + bv.z, 0.0f);
                const float v3 = fmaxf(a1[mt][sg][3] + bv.w, 0.0f);
                uint2 pk; pk.x = pack2bf(v0, v1); pk.y = pack2bf(v2, v3);
                *reinterpret_cast<uint2*>(&actA[w][sg * 16 + n][mt * 16 + quad * 4]) = pk;
            }
        }
    }
    __syncthreads();

    // ---- L2: 256 -> 256 ----
    {
        f32x4 a2[16][2];
        #pragma unroll
        for (int mt = 0; mt < 16; ++mt) { a2[mt][0] = zero4; a2[mt][1] = zero4; }
        #pragma unroll
        for (int kt = 0; kt < 8; ++kt) {
            const bh8 b0 = *reinterpret_cast<const bh8*>(&actA[w][n][kt * 32 + quad * 8]);
            const bh8 b1 = *reinterpret_cast<const bh8*>(&actA[w][16 + n][kt * 32 + quad * 8]);
            #pragma unroll
            for (int mt = 0; mt < 16; ++mt) {
                const bh8 a = *reinterpret_cast<const bh8*>(
                    w2f + (size_t)((kt * 16 + mt) * 64 + lane) * 8);
                a2[mt][0] = __builtin_amdgcn_mfma_f32_16x16x32_bf16(a, b0, a2[mt][0], 0, 0, 0);
                a2[mt][1] = __builtin_amdgcn_mfma_f32_16x16x32_bf16(a, b1, a2[mt][1], 0, 0, 0);
            }
        }
        #pragma unroll
        for (int mt = 0; mt < 16; ++mt) {
            const float4 bv = *reinterpret_cast<const float4*>(B2 + mt * 16 + quad * 4);
            #pragma unroll
            for (int sg = 0; sg < 2; ++sg) {
                const float v0 = fmaxf(a2[mt][sg][0] + bv.x, 0.0f);
                const float v1 = fmaxf(a2[mt][sg][1] + bv.y, 0.0f);
                const float v2 = fmaxf(a2[mt][sg][2] + bv.z, 0.0f);
                const float v3 = fmaxf(a2[mt][sg][3] + bv.w, 0.0f);
                uint2 pk; pk.x = pack2bf(v0, v1); pk.y = pack2bf(v2, v3);
                *reinterpret_cast<uint2*>(&actB[w][sg * 16 + n][mt * 16 + quad * 4]) = pk;
            }
        }
    }
    __syncthreads();

    // ---- L3: 256 -> 128 ----
    {
        f32x4 a3[8][2];
        #pragma unroll
        for (int mt = 0; mt < 8; ++mt) { a3[mt][0] = zero4; a3[mt][1] = zero4; }
        #pragma unroll
        for (int kt = 0; kt < 8; ++kt) {
            const bh8 b0 = *reinterpret_cast<const bh8*>(&actB[w][n][kt * 32 + quad * 8]);
            const bh8 b1 = *reinterpret_cast<const bh8*>(&actB[w][16 + n][kt * 32 + quad * 8]);
            #pragma unroll
            for (int mt = 0; mt < 8; ++mt) {
                const bh8 a = *reinterpret_cast<const bh8*>(
                    w3f + (size_t)((kt * 8 + mt) * 64 + lane) * 8);
                a3[mt][0] = __builtin_amdgcn_mfma_f32_16x16x32_bf16(a, b0, a3[mt][0], 0, 0, 0);
                a3[mt][1] = __builtin_amdgcn_mfma_f32_16x16x32_bf16(a, b1, a3[mt][1], 0, 0, 0);
            }
        }
        #pragma unroll
        for (int mt = 0; mt < 8; ++mt) {
            const float4 bv = *reinterpret_cast<const float4*>(B3 + mt * 16 + quad * 4);
            #pragma unroll
            for (int sg = 0; sg < 2; ++sg) {
                const float v0 = fmaxf(a3[mt][sg][0] + bv.x, 0.0f);
                const float v1 = fmaxf(a3[mt][sg][1] + bv.y, 0.0f);
                const float v2 = fmaxf(a3[mt][sg][2] + bv.z, 0.0f);
                const float v3 = fmaxf(a3[mt][sg][3] + bv.w, 0.0f);
                uint2 pk; pk.x = pack2bf(v0, v1); pk.y = pack2bf(v2, v3);
                *reinterpret_cast<uint2*>(&actA[w][sg * 16 + n][mt * 16 + quad * 4]) = pk;
            }
        }
    }
    __syncthreads();

    // ---- L4: 128 -> 16, write f16 to xcat ----
    {
        f32x4 a4[2] = {zero4, zero4};
        #pragma unroll
        for (int kt = 0; kt < 4; ++kt) {
            const bh8 b0 = *reinterpret_cast<const bh8*>(&actA[w][n][kt * 32 + quad * 8]);
            const bh8 b1 = *reinterpret_cast<const bh8*>(&actA[w][16 + n][kt * 32 + quad * 8]);
            const bh8 a = *reinterpret_cast<const bh8*>(w4f + (size_t)(kt * 64 + lane) * 8);
            a4[0] = __builtin_amdgcn_mfma_f32_16x16x32_bf16(a, b0, a4[0], 0, 0, 0);
            a4[1] = __builtin_amdgcn_mfma_f32_16x16x32_bf16(a, b1, a4[1], 0, 0, 0);
        }
        const float4 bv = *reinterpret_cast<const float4*>(B4 + quad * 4);
        #pragma unroll
        for (int sg = 0; sg < 2; ++sg) {
            const int grow = wrow0 + sg * 16 + n;
            const float v0 = fmaxf(a4[sg][0] + bv.x, 0.0f);
            const float v1 = fmaxf(a4[sg][1] + bv.y, 0.0f);
            const float v2 = fmaxf(a4[sg][2] + bv.z, 0.0f);
            const float v3 = fmaxf(a4[sg][3] + bv.w, 0.0f);
            uint2 pk; pk.x = pack2h(v0, v1); pk.y = pack2h(v2, v3);
            *reinterpret_cast<uint2*>(xcat_h + (size_t)grow * XH_STRIDE + quad * 4) = pk;
        }
    }
}

// ===========================================================================
// LSTM scan v3: 256 blocks x 2 batch-cols, 256 threads (4 waves).
// Per step: gates[512x16(2 real)] = Wc[512x160] @ [h;x][160x16] via f16 MFMA;
// wave w holds A-frags for mtiles {g*8+w, g*8+w+4}. Lanes n<2 transpose-write
// biased gates to gbuf; each thread then owns exactly 1 (col,unit) tuple ->
// 10 transcendentals/lane (was 40). hx double-buffered, 2 barriers/step.
// ===========================================================================
#define COLS 2
#define HXS 168      // hx row stride in shorts

__global__ __launch_bounds__(256) void lstm_kernel(
    const unsigned short* __restrict__ xcat_h,
    const int*   __restrict__ done,
    const float* __restrict__ h0,
    const float* __restrict__ c0,
    const unsigned short* __restrict__ wcf,   // A-frag blob [32][5][64][8] f16
    const float* __restrict__ bsum,           // [512] = bih + bhh
    float* __restrict__ out)
{
    __shared__ __align__(16) unsigned short hx[2][16][HXS];
    __shared__ __align__(16) float gbuf[COLS][130][4];

    const int tid  = threadIdx.x;
    const int w    = tid >> 6;        // wave 0..3
    const int lane = tid & 63;
    const int n    = lane & 15;       // batch column (0..1 real)
    const int quad = lane >> 4;
    const int bb   = blockIdx.x * COLS;

    // A-frags: mtiles g*8 + (w + 4*h), g in 0..3, h in 0..1  (160 VGPRs)
    h8 wf[2][4][5];
    #pragma unroll
    for (int h = 0; h < 2; ++h)
        #pragma unroll
        for (int g = 0; g < 4; ++g)
            #pragma unroll
            for (int kt = 0; kt < 5; ++kt)
                wf[h][g][kt] = *reinterpret_cast<const h8*>(
                    wcf + (size_t)(((g * 8 + w + 4 * h) * 5 + kt) * 64 + lane) * 8);

    // tuple ownership: thread -> (col tn, unit tu)
    const int tn = tid >> 7;          // 0..1
    const int tu = tid & 127;
    float bi_t[4];
    #pragma unroll
    for (int g = 0; g < 4; ++g) bi_t[g] = bsum[g * 128 + tu];

    float c_ = c0[(size_t)(bb + tn) * HID + tu];
    const float h0v = h0[(size_t)(bb + tn) * HID + tu];

    // zero both hx buffers (cols 2..15 stay zero; pads k=152..159 stay zero)
    for (int i = tid; i < 2 * 16 * HXS / 2; i += 256)
        reinterpret_cast<unsigned int*>(hx)[i] = 0u;
    __syncthreads();

    int mc = done[bb + tn];
    int mn = done[BATCH + bb + tn];
    hx[0][tn][tu] = f2h_bits(h0v * (1.0f - (float)mc));
    if (tid < COLS * 12) {
        const int nl = tid / 12, kp = tid - nl * 12;
        *reinterpret_cast<unsigned int*>(&hx[0][nl][128 + 2 * kp]) =
            *reinterpret_cast<const unsigned int*>(
                xcat_h + (size_t)(bb + nl) * XH_STRIDE + 2 * kp);
    }
    __syncthreads();

    float hl = 0.0f;

    #pragma unroll 1
    for (int s = 0; s < T_STEPS; ++s) {
        const int buf = s & 1;

        // B-frags for col n
        h8 bf[5];
        #pragma unroll
        for (int kt = 0; kt < 5; ++kt)
            bf[kt] = *reinterpret_cast<const h8*>(&hx[buf][n][kt * 32 + quad * 8]);

        // prefetch x(s+1) and done(s+2)
        unsigned int xreg = 0;
        if (tid < COLS * 12) {
            const int nl = tid / 12, kp = tid - nl * 12;
            const int rowx = (s + 1 < T_STEPS ? s + 1 : T_STEPS - 1) * BATCH + bb + nl;
            xreg = *reinterpret_cast<const unsigned int*>(
                xcat_h + (size_t)rowx * XH_STRIDE + 2 * kp);
        }
        const int mf = done[(s + 2 < T_STEPS ? s + 2 : T_STEPS - 1) * BATCH + bb + tn];

        // MFMA: gates = Wc @ [h;x]
        f32x4 acc[2][4];
        #pragma unroll
        for (int h = 0; h < 2; ++h)
            #pragma unroll
            for (int g = 0; g < 4; ++g) acc[h][g] = (f32x4){0.0f, 0.0f, 0.0f, 0.0f};
        #pragma unroll
        for (int kt = 0; kt < 5; ++kt)
            #pragma unroll
            for (int h = 0; h < 2; ++h)
                #pragma unroll
                for (int g = 0; g < 4; ++g)
                    acc[h][g] = __builtin_amdgcn_mfma_f32_16x16x32_f16(
                        wf[h][g][kt], bf[kt], acc[h][g], 0, 0, 0);

        // transpose-write gates to gbuf (real cols only)
        if (n < COLS) {
            #pragma unroll
            for (int h = 0; h < 2; ++h) {
                const int ub = (w + 4 * h) * 16 + quad * 4;
                #pragma unroll
                for (int r = 0; r < 4; ++r) {
                    float4 gv;
                    gv.x = acc[h][0][r]; gv.y = acc[h][1][r];
                    gv.z = acc[h][2][r]; gv.w = acc[h][3][r];
                    *reinterpret_cast<float4*>(&gbuf[n][ub + r][0]) = gv;
                }
            }
        }
        __syncthreads();

        // gate math: 1 tuple per thread
        const float4 gv = *reinterpret_cast<const float4*>(&gbuf[tn][tu][0]);
        const float mcur = 1.0f - (float)mc;
        const float mnxt = 1.0f - (float)mn;
        const float gi = gv.x + bi_t[0];
        const float gf = gv.y + bi_t[1];
        const float gg = gv.z + bi_t[2];
        const float go = gv.w + bi_t[3];
        const float cn = sigf(gf) * (c_ * mcur) + sigf(gi) * tanh_fast(gg);
        const float hn = sigf(go) * tanh_fast(cn);
        c_ = cn; hl = hn;

        const int row = s * BATCH + bb + tn;
        out[(size_t)row * HID + tu] = hn;
        hx[buf ^ 1][tn][tu] = f2h_bits(hn * mnxt);
        if (tid < COLS * 12) {
            const int nl = tid / 12, kp = tid - nl * 12;
            *reinterpret_cast<unsigned int*>(&hx[buf ^ 1][nl][128 + 2 * kp]) = xreg;
        }
        mc = mn; mn = mf;
        __syncthreads();
    }

    const size_t base = (size_t)TBROWS * HID;
    out[base + (size_t)(bb + tn) * HID + tu] = hl;
    out[base + (size_t)BATCH * HID + (size_t)(bb + tn) * HID + tu] = c_;
}

// ===========================================================================
extern "C" void kernel_launch(void* const* d_in, const int* in_sizes, int n_in,
                              void* d_out, int out_size, void* d_ws, size_t ws_size,
                              hipStream_t stream) {
    const float* img  = (const float*)d_in[0];
    const float* loc  = (const float*)d_in[1];
    const float* msg  = (const float*)d_in[2];
    const int*   done = (const int*)d_in[3];
    const float* h0   = (const float*)d_in[4];
    const float* c0   = (const float*)d_in[5];
    const float* W1   = (const float*)d_in[6];
    const float* B1   = (const float*)d_in[7];
    const float* W2   = (const float*)d_in[8];
    const float* B2   = (const float*)d_in[9];
    const float* W3   = (const float*)d_in[10];
    const float* B3   = (const float*)d_in[11];
    const float* W4   = (const float*)d_in[12];
    const float* B4   = (const float*)d_in[13];
    const float* Wl   = (const float*)d_in[14];
    const float* Bl   = (const float*)d_in[15];
    const float* Wm   = (const float*)d_in[16];
    const float* Bm   = (const float*)d_in[17];
    const float* Wih  = (const float*)d_in[18];
    const float* bih  = (const float*)d_in[19];
    const float* Whh  = (const float*)d_in[20];
    const float* bhh  = (const float*)d_in[21];

    // workspace layout
    char* wsb = (char*)d_ws;
    unsigned short* xcat_h = (unsigned short*)wsb;                   // 8 388 608 B
    unsigned short* w1f = (unsigned short*)(wsb + (size_t)TBROWS * XH_STRIDE * 2);
    unsigned short* w2f = w1f + NE1;
    unsigned short* w3f = w2f + NE2;
    unsigned short* w4f = w3f + NE3;
    unsigned short* wcf = w4f + NE4;
    float*          bsum = (float*)(wcf + NWC);

    float* out = (float*)d_out;

    prep_kernel<<<(PREP_TOTAL + 255) / 256, 256, 0, stream>>>(
        W1, W2, W3, W4, Wih, bih, Whh, bhh,
        w1f, w2f, w3f, w4f, wcf, bsum);
    encoder_kernel<<<TBROWS / 128, 256, 0, stream>>>(
        img, loc, msg, done, B1, B2, B3, B4, Wl, Bl, Wm, Bm,
        w1f, w2f, w3f, w4f, xcat_h);
    lstm_kernel<<<BATCH / COLS, 256, 0, stream>>>(
        xcat_h, done, h0, c0, wcf, bsum, out);
}